// Round 12
// baseline (133.079 us; speedup 1.0000x reference)
//
#include <hip/hip_runtime.h>

#define IN_DIM   4096
#define OUT_DIM  4096
#define FAN_IN   64
#define ROWS     8
#define NTHREADS 512
#define O_PER_THREAD (OUT_DIM / NTHREADS) // 8
#define MT_BYTES ((size_t)(FAN_IN / 4) * OUT_DIM * 16)  // 1 MB per table

typedef __fp16 v2h __attribute__((ext_vector_type(2)));

// Bijective 16B-block swizzle: spreads LDS bank-start groups.
__device__ __forceinline__ int bswz(int m) {
    return (m & ~7) | ((m ^ (m >> 3)) & 7);
}

// pack two f32 -> two f16 (RTZ) in one v_cvt_pkrtz_f16_f32
__device__ __forceinline__ unsigned int pack_f16(float a, float b) {
    v2h h = __builtin_amdgcn_cvt_pkrtz(a, b);
    unsigned int u;
    __builtin_memcpy(&u, &h, sizeof(u));
    return u;
}

// Bank-group scheduling preprocessor: one thread per output.
// Reorders each output's 64 (mask, weight) pairs so that slot s draws a mask
// whose LDS bank-group is (s + o) % 8 when possible. Since lane l of the
// slot-s gather instruction handles output o = const + l, this makes every
// ds_read_b128 spread its 64 lanes 8-per-bank-group = zero-conflict minimum.
// Greedy fallback: steal from the group with most remaining (deterministic).
// Sum order changes only (fp-associativity; well within threshold).
__global__ __launch_bounds__(256)
void schedule_mw(const int* __restrict__ M, const float* __restrict__ W,
                 int4* __restrict__ Mt, float4* __restrict__ Wt)
{
    const int o = blockIdx.x * 256 + threadIdx.x;   // [0, 4096)

    int   mm[FAN_IN];
    float ww[FAN_IN];
    int   gg[FAN_IN];
    for (int k = 0; k < FAN_IN; ++k) {
        const int m = M[(size_t)o * FAN_IN + k];
        mm[k] = bswz(m) << 4;            // pre-swizzled BYTE offset
        gg[k] = (mm[k] >> 4) & 7;        // bank group 0..7
        ww[k] = W[(size_t)o * FAN_IN + k];
    }
    // counting sort by group
    int cnt[8] = {0,0,0,0,0,0,0,0};
    for (int k = 0; k < FAN_IN; ++k) cnt[gg[k]]++;
    int start[8]; int acc0 = 0;
    for (int g = 0; g < 8; ++g) { start[g] = acc0; acc0 += cnt[g]; }
    int fill[8] = {0,0,0,0,0,0,0,0};
    int order[FAN_IN];
    for (int k = 0; k < FAN_IN; ++k) order[start[gg[k]] + fill[gg[k]]++] = k;
    // greedy staggered schedule
    int ptr[8] = {0,0,0,0,0,0,0,0};
    int4 tm; float4 tw;
    for (int s = 0; s < FAN_IN; ++s) {
        int d = (s + o) & 7;
        if (ptr[d] >= cnt[d]) {
            int best = 0, bestrem = -1;
            for (int g = 0; g < 8; ++g) {
                const int rem = cnt[g] - ptr[g];
                if (rem > bestrem) { bestrem = rem; best = g; }
            }
            d = best;
        }
        const int k = order[start[d] + ptr[d]++];
        ((int*)&tm)[s & 3]   = mm[k];
        ((float*)&tw)[s & 3] = ww[k];
        if ((s & 3) == 3) {
            Mt[(s >> 2) * OUT_DIM + o] = tm;
            Wt[(s >> 2) * OUT_DIM + o] = tw;
        }
    }
}

// v_fma_mix_f32: acc += (f16 half of pk) * w   (f16->f32 convert exact, fma in f32)
#define FMAMIX_LO(acc, pk, w)                                                  \
    asm("v_fma_mix_f32 %0, %1, %2, %0 op_sel:[0,0,0] op_sel_hi:[1,0,0]"        \
        : "+v"(acc) : "v"(pk), "v"(w))
#define FMAMIX_HI(acc, pk, w)                                                  \
    asm("v_fma_mix_f32 %0, %1, %2, %0 op_sel:[1,0,0] op_sel_hi:[1,0,0]"        \
        : "+v"(acc) : "v"(pk), "v"(w))

// 64 KiB LDS -> 2 blocks/CU (LDS-capped, 16 waves/CU). VGPR cap 128.
template <bool TRANSPOSED>
__global__ __launch_bounds__(NTHREADS, 4)
void ffi_sparse_kernel(const float* __restrict__ inp,
                       const float* __restrict__ W,
                       const int*   __restrict__ M,
                       const float* __restrict__ bias,
                       const int4*  __restrict__ Mt,
                       const float4* __restrict__ Wt,
                       float* __restrict__ out)
{
    // [col][8 rows] packed f16 pairs: one uint4 (16 B) per column. 64 KiB.
    __shared__ unsigned int lds[IN_DIM * ROWS / 2];

    const int tid = threadIdx.x;
    const int r0  = blockIdx.x * ROWS;

    // ---------------- stage: 8 rows x 4096 cols, f32 -> f16, transpose ----------------
    #pragma unroll
    for (int t = 0; t < (ROWS * IN_DIM / 16) / NTHREADS; ++t) {   // 4 iterations
        const int tile = tid + t * NTHREADS;     // 0..2047
        const int rblk = tile >> 10;             // 0..1
        const int c4   = (tile & 1023) << 2;     // column base
        const float* src = inp + (size_t)(r0 + rblk * 4) * IN_DIM + c4;
        const float4 v0 = *(const float4*)(src);
        const float4 v1 = *(const float4*)(src + IN_DIM);
        const float4 v2 = *(const float4*)(src + 2 * IN_DIM);
        const float4 v3 = *(const float4*)(src + 3 * IN_DIM);

        unsigned int* p;
        p = lds + bswz(c4 + 0) * 4 + rblk * 2;
        *(uint2*)p = make_uint2(pack_f16(v0.x, v1.x), pack_f16(v2.x, v3.x));
        p = lds + bswz(c4 + 1) * 4 + rblk * 2;
        *(uint2*)p = make_uint2(pack_f16(v0.y, v1.y), pack_f16(v2.y, v3.y));
        p = lds + bswz(c4 + 2) * 4 + rblk * 2;
        *(uint2*)p = make_uint2(pack_f16(v0.z, v1.z), pack_f16(v2.z, v3.z));
        p = lds + bswz(c4 + 3) * 4 + rblk * 2;
        *(uint2*)p = make_uint2(pack_f16(v0.w, v1.w), pack_f16(v2.w, v3.w));
    }
    __syncthreads();

    const char* __restrict__ ldsb = (const char*)lds;

#define LDQ(off) (*(const uint4*)(ldsb + (off)))

    // 8 x v_fma_mix_f32 per (o,k): zero unpack instructions.
#define CONSUME(d, wv) {                                                       \
        FMAMIX_LO(acc0, d.x, wv);  FMAMIX_HI(acc1, d.x, wv);                   \
        FMAMIX_LO(acc2, d.y, wv);  FMAMIX_HI(acc3, d.y, wv);                   \
        FMAMIX_LO(acc4, d.z, wv);  FMAMIX_HI(acc5, d.z, wv);                   \
        FMAMIX_LO(acc6, d.w, wv);  FMAMIX_HI(acc7, d.w, wv);                   \
    }
#define ISSUE4(D0,D1,D2,D3, MN) {                                              \
        D0 = LDQ(MN.x); D1 = LDQ(MN.y); D2 = LDQ(MN.z); D3 = LDQ(MN.w); }
#define CONS4(D0,D1,D2,D3, WC) {                                               \
        CONSUME(D0, WC.x); CONSUME(D1, WC.y);                                  \
        CONSUME(D2, WC.z); CONSUME(D3, WC.w); }
#define MWLD(dm, dw, idx) {                                                    \
        if (TRANSPOSED) {                                                      \
            dm = Mt[(idx) * OUT_DIM + o];                                      \
            dw = Wt[(idx) * OUT_DIM + o];                                      \
        } else {                                                               \
            int4 mr = mp[(idx)];                                               \
            mr.x = bswz(mr.x) << 4; mr.y = bswz(mr.y) << 4;                    \
            mr.z = bswz(mr.z) << 4; mr.w = bswz(mr.w) << 4;                    \
            dm = mr; dw = wp[(idx)];                                           \
        } }

    // Cyclic output mapping -> coalesced stores and coalesced Mt/Wt loads.
    #pragma unroll 1
    for (int i = 0; i < O_PER_THREAD; ++i) {
        const int o = tid + i * NTHREADS;
        const float bv = bias[o];
        float acc0 = bv, acc1 = bv, acc2 = bv, acc3 = bv;
        float acc4 = bv, acc5 = bv, acc6 = bv, acc7 = bv;

        const int4*   mp = (const int4*)(M + (size_t)o * FAN_IN);   // fallback
        const float4* wp = (const float4*)(W + (size_t)o * FAN_IN);

        // Straight-line 3-stage pipeline, named registers only (no arrays ->
        // no possible scratch). Trip c: issue ds-reads for c+1, prefetch
        // Mt/Wt[c+3], consume c. Buffers alternate dA/dB; m/w are a 4-ring.
        int4   m0, m1, m2, m3;
        float4 w0, w1, w2, w3;
        uint4  dA0, dA1, dA2, dA3, dB0, dB1, dB2, dB3;

        MWLD(m0, w0, 0);  MWLD(m1, w1, 1);  MWLD(m2, w2, 2);
        ISSUE4(dA0,dA1,dA2,dA3, m0);                                   // trip 0 data

        ISSUE4(dB0,dB1,dB2,dB3, m1);  MWLD(m3,w3, 3);   CONS4(dA0,dA1,dA2,dA3, w0);  // c=0
        ISSUE4(dA0,dA1,dA2,dA3, m2);  MWLD(m0,w0, 4);   CONS4(dB0,dB1,dB2,dB3, w1);  // c=1
        ISSUE4(dB0,dB1,dB2,dB3, m3);  MWLD(m1,w1, 5);   CONS4(dA0,dA1,dA2,dA3, w2);  // c=2
        ISSUE4(dA0,dA1,dA2,dA3, m0);  MWLD(m2,w2, 6);   CONS4(dB0,dB1,dB2,dB3, w3);  // c=3
        ISSUE4(dB0,dB1,dB2,dB3, m1);  MWLD(m3,w3, 7);   CONS4(dA0,dA1,dA2,dA3, w0);  // c=4
        ISSUE4(dA0,dA1,dA2,dA3, m2);  MWLD(m0,w0, 8);   CONS4(dB0,dB1,dB2,dB3, w1);  // c=5
        ISSUE4(dB0,dB1,dB2,dB3, m3);  MWLD(m1,w1, 9);   CONS4(dA0,dA1,dA2,dA3, w2);  // c=6
        ISSUE4(dA0,dA1,dA2,dA3, m0);  MWLD(m2,w2,10);   CONS4(dB0,dB1,dB2,dB3, w3);  // c=7
        ISSUE4(dB0,dB1,dB2,dB3, m1);  MWLD(m3,w3,11);   CONS4(dA0,dA1,dA2,dA3, w0);  // c=8
        ISSUE4(dA0,dA1,dA2,dA3, m2);  MWLD(m0,w0,12);   CONS4(dB0,dB1,dB2,dB3, w1);  // c=9
        ISSUE4(dB0,dB1,dB2,dB3, m3);  MWLD(m1,w1,13);   CONS4(dA0,dA1,dA2,dA3, w2);  // c=10
        ISSUE4(dA0,dA1,dA2,dA3, m0);  MWLD(m2,w2,14);   CONS4(dB0,dB1,dB2,dB3, w3);  // c=11
        ISSUE4(dB0,dB1,dB2,dB3, m1);  MWLD(m3,w3,15);   CONS4(dA0,dA1,dA2,dA3, w0);  // c=12
        ISSUE4(dA0,dA1,dA2,dA3, m2);                    CONS4(dB0,dB1,dB2,dB3, w1);  // c=13
        ISSUE4(dB0,dB1,dB2,dB3, m3);                    CONS4(dA0,dA1,dA2,dA3, w2);  // c=14
                                                        CONS4(dB0,dB1,dB2,dB3, w3);  // c=15

        float* op = out + (size_t)r0 * OUT_DIM + o;
        op[0 * OUT_DIM] = acc0;
        op[1 * OUT_DIM] = acc1;
        op[2 * OUT_DIM] = acc2;
        op[3 * OUT_DIM] = acc3;
        op[4 * OUT_DIM] = acc4;
        op[5 * OUT_DIM] = acc5;
        op[6 * OUT_DIM] = acc6;
        op[7 * OUT_DIM] = acc7;
    }
#undef CONSUME
#undef ISSUE4
#undef CONS4
#undef MWLD
#undef LDQ
}

extern "C" void kernel_launch(void* const* d_in, const int* in_sizes, int n_in,
                              void* d_out, int out_size, void* d_ws, size_t ws_size,
                              hipStream_t stream) {
    const float* inp  = (const float*)d_in[0];
    const float* W    = (const float*)d_in[1];
    const int*   M    = (const int*)d_in[2];
    const float* bias = (const float*)d_in[3];
    float* out = (float*)d_out;

    const int n_rows = in_sizes[0] / IN_DIM;          // 4096
    dim3 grid(n_rows / ROWS), block(NTHREADS);

    const bool use_t = ws_size >= 2 * MT_BYTES;
    if (use_t) {
        int4*   Mt = (int4*)d_ws;
        float4* Wt = (float4*)((char*)d_ws + MT_BYTES);
        schedule_mw<<<dim3(OUT_DIM / 256), dim3(256), 0, stream>>>(M, W, Mt, Wt);
        ffi_sparse_kernel<true><<<grid, block, 0, stream>>>(inp, W, M, bias, Mt, Wt, out);
    } else {
        ffi_sparse_kernel<false><<<grid, block, 0, stream>>>(inp, W, M, bias,
                                                             (const int4*)nullptr,
                                                             (const float4*)nullptr, out);
    }
}

// Round 13
// 71.989 us; speedup vs baseline: 1.8486x; 1.8486x over previous
//
#include <hip/hip_runtime.h>

#define IN_DIM   4096
#define OUT_DIM  4096
#define FAN_IN   64
#define ROWS     8
#define NTHREADS 512
#define O_PER_THREAD (OUT_DIM / NTHREADS) // 8
#define MT_BYTES ((size_t)(FAN_IN / 4) * OUT_DIM * 16)  // 1 MB per table

typedef __fp16 v2h __attribute__((ext_vector_type(2)));

// Bijective 16B-block swizzle: spreads LDS bank-start groups.
__device__ __forceinline__ int bswz(int m) {
    return (m & ~7) | ((m ^ (m >> 3)) & 7);
}

// pack two f32 -> two f16 (RTZ) in one v_cvt_pkrtz_f16_f32
__device__ __forceinline__ unsigned int pack_f16(float a, float b) {
    v2h h = __builtin_amdgcn_cvt_pkrtz(a, b);
    unsigned int u;
    __builtin_memcpy(&u, &h, sizeof(u));
    return u;
}

// Wave-parallel bank-group scheduler: ONE WAVE PER OUTPUT, zero arrays.
// Lane k owns element k of output o. Ballot-derived group counts/ranks give a
// bijective slot permutation where slot s preferentially holds a mask of bank
// group (s+o)&7; since the main kernel's slot-s gather has lane l on output
// o=base+l, all 64 lanes spread 8-per-group => near-zero LDS conflicts.
// Overflow elements (in-group rank >= 8) fill the holes in (h,j) order.
__global__ __launch_bounds__(256)
void schedule_mw(const int* __restrict__ M, const float* __restrict__ W,
                 int* __restrict__ Mt, float* __restrict__ Wt)
{
    const int o = blockIdx.x * 4 + (threadIdx.x >> 6);   // 4 waves/block
    const int k = threadIdx.x & 63;

    const int   m    = M[(size_t)o * FAN_IN + k];
    const float w    = W[(size_t)o * FAN_IN + k];
    const int   moff = bswz(m) << 4;       // pre-swizzled byte offset
    const int   g    = (moff >> 4) & 7;    // bank group

    // group counts (all lanes get full vector) + own-group mask
    int cnt[8];
    unsigned long long same = 0;
    #pragma unroll
    for (int h = 0; h < 8; ++h) {
        const unsigned long long b = __ballot(g == h);
        cnt[h] = __popcll(b);
        if (g == h) same = b;
    }
    const unsigned long long ltmask = (k == 0) ? 0ULL : (~0ULL >> (64 - k));
    const int r = __popcll(same & ltmask);         // rank within my group

    int slot;
    if (r < 8) {
        slot = ((g - o) & 7) + 8 * r;              // staggered target slot
    } else {
        int ovr = r - 8;                           // overflow rank
        #pragma unroll
        for (int h = 0; h < 8; ++h)
            if (h < g && cnt[h] > 8) ovr += cnt[h] - 8;
        int hstar = 0, jstar = 0, rem = ovr;
        bool found = false;
        #pragma unroll
        for (int h = 0; h < 8; ++h) {
            const int nh = (cnt[h] < 8) ? (8 - cnt[h]) : 0;
            if (!found && rem < nh) { hstar = h; jstar = cnt[h] + rem; found = true; }
            if (!found) rem -= nh;
        }
        slot = ((hstar - o) & 7) + 8 * jstar;      // fill hole
    }

    // scatter into [kk][o] int4-compatible layout
    const int idx = ((slot >> 2) * OUT_DIM + o) * 4 + (slot & 3);
    Mt[idx] = moff;
    Wt[idx] = w;
}

// v_fma_mix_f32: acc += (f16 half of pk) * w   (f16->f32 convert exact, fma in f32)
#define FMAMIX_LO(acc, pk, w)                                                  \
    asm("v_fma_mix_f32 %0, %1, %2, %0 op_sel:[0,0,0] op_sel_hi:[1,0,0]"        \
        : "+v"(acc) : "v"(pk), "v"(w))
#define FMAMIX_HI(acc, pk, w)                                                  \
    asm("v_fma_mix_f32 %0, %1, %2, %0 op_sel:[1,0,0] op_sel_hi:[1,0,0]"        \
        : "+v"(acc) : "v"(pk), "v"(w))

// 64 KiB LDS -> 2 blocks/CU (LDS-capped, 16 waves/CU). VGPR cap 128.
template <bool TRANSPOSED>
__global__ __launch_bounds__(NTHREADS, 4)
void ffi_sparse_kernel(const float* __restrict__ inp,
                       const float* __restrict__ W,
                       const int*   __restrict__ M,
                       const float* __restrict__ bias,
                       const int4*  __restrict__ Mt,
                       const float4* __restrict__ Wt,
                       float* __restrict__ out)
{
    // [col][8 rows] packed f16 pairs: one uint4 (16 B) per column. 64 KiB.
    __shared__ unsigned int lds[IN_DIM * ROWS / 2];

    const int tid = threadIdx.x;
    const int r0  = blockIdx.x * ROWS;

    // ---------------- stage: 8 rows x 4096 cols, f32 -> f16, transpose ----------------
    #pragma unroll
    for (int t = 0; t < (ROWS * IN_DIM / 16) / NTHREADS; ++t) {   // 4 iterations
        const int tile = tid + t * NTHREADS;     // 0..2047
        const int rblk = tile >> 10;             // 0..1
        const int c4   = (tile & 1023) << 2;     // column base
        const float* src = inp + (size_t)(r0 + rblk * 4) * IN_DIM + c4;
        const float4 v0 = *(const float4*)(src);
        const float4 v1 = *(const float4*)(src + IN_DIM);
        const float4 v2 = *(const float4*)(src + 2 * IN_DIM);
        const float4 v3 = *(const float4*)(src + 3 * IN_DIM);

        unsigned int* p;
        p = lds + bswz(c4 + 0) * 4 + rblk * 2;
        *(uint2*)p = make_uint2(pack_f16(v0.x, v1.x), pack_f16(v2.x, v3.x));
        p = lds + bswz(c4 + 1) * 4 + rblk * 2;
        *(uint2*)p = make_uint2(pack_f16(v0.y, v1.y), pack_f16(v2.y, v3.y));
        p = lds + bswz(c4 + 2) * 4 + rblk * 2;
        *(uint2*)p = make_uint2(pack_f16(v0.z, v1.z), pack_f16(v2.z, v3.z));
        p = lds + bswz(c4 + 3) * 4 + rblk * 2;
        *(uint2*)p = make_uint2(pack_f16(v0.w, v1.w), pack_f16(v2.w, v3.w));
    }
    __syncthreads();

    const char* __restrict__ ldsb = (const char*)lds;

#define LDQ(off) (*(const uint4*)(ldsb + (off)))

    // 8 x v_fma_mix_f32 per (o,k): zero unpack instructions.
#define CONSUME(d, wv) {                                                       \
        FMAMIX_LO(acc0, d.x, wv);  FMAMIX_HI(acc1, d.x, wv);                   \
        FMAMIX_LO(acc2, d.y, wv);  FMAMIX_HI(acc3, d.y, wv);                   \
        FMAMIX_LO(acc4, d.z, wv);  FMAMIX_HI(acc5, d.z, wv);                   \
        FMAMIX_LO(acc6, d.w, wv);  FMAMIX_HI(acc7, d.w, wv);                   \
    }
#define ISSUE4(D0,D1,D2,D3, MN) {                                              \
        D0 = LDQ(MN.x); D1 = LDQ(MN.y); D2 = LDQ(MN.z); D3 = LDQ(MN.w); }
#define CONS4(D0,D1,D2,D3, WC) {                                               \
        CONSUME(D0, WC.x); CONSUME(D1, WC.y);                                  \
        CONSUME(D2, WC.z); CONSUME(D3, WC.w); }
#define MWLD(dm, dw, idx) {                                                    \
        if (TRANSPOSED) {                                                      \
            dm = Mt[(idx) * OUT_DIM + o];                                      \
            dw = Wt[(idx) * OUT_DIM + o];                                      \
        } else {                                                               \
            int4 mr = mp[(idx)];                                               \
            mr.x = bswz(mr.x) << 4; mr.y = bswz(mr.y) << 4;                    \
            mr.z = bswz(mr.z) << 4; mr.w = bswz(mr.w) << 4;                    \
            dm = mr; dw = wp[(idx)];                                           \
        } }

    // Cyclic output mapping -> coalesced stores and coalesced Mt/Wt loads.
    #pragma unroll 1
    for (int i = 0; i < O_PER_THREAD; ++i) {
        const int o = tid + i * NTHREADS;
        const float bv = bias[o];
        float acc0 = bv, acc1 = bv, acc2 = bv, acc3 = bv;
        float acc4 = bv, acc5 = bv, acc6 = bv, acc7 = bv;

        const int4*   mp = (const int4*)(M + (size_t)o * FAN_IN);   // fallback
        const float4* wp = (const float4*)(W + (size_t)o * FAN_IN);

        // Straight-line 3-stage pipeline, named registers only (no arrays ->
        // no possible scratch). Trip c: issue ds-reads for c+1, prefetch
        // Mt/Wt[c+3], consume c. Buffers alternate dA/dB; m/w are a 4-ring.
        int4   m0, m1, m2, m3;
        float4 w0, w1, w2, w3;
        uint4  dA0, dA1, dA2, dA3, dB0, dB1, dB2, dB3;

        MWLD(m0, w0, 0);  MWLD(m1, w1, 1);  MWLD(m2, w2, 2);
        ISSUE4(dA0,dA1,dA2,dA3, m0);                                   // trip 0 data

        ISSUE4(dB0,dB1,dB2,dB3, m1);  MWLD(m3,w3, 3);   CONS4(dA0,dA1,dA2,dA3, w0);  // c=0
        ISSUE4(dA0,dA1,dA2,dA3, m2);  MWLD(m0,w0, 4);   CONS4(dB0,dB1,dB2,dB3, w1);  // c=1
        ISSUE4(dB0,dB1,dB2,dB3, m3);  MWLD(m1,w1, 5);   CONS4(dA0,dA1,dA2,dA3, w2);  // c=2
        ISSUE4(dA0,dA1,dA2,dA3, m0);  MWLD(m2,w2, 6);   CONS4(dB0,dB1,dB2,dB3, w3);  // c=3
        ISSUE4(dB0,dB1,dB2,dB3, m1);  MWLD(m3,w3, 7);   CONS4(dA0,dA1,dA2,dA3, w0);  // c=4
        ISSUE4(dA0,dA1,dA2,dA3, m2);  MWLD(m0,w0, 8);   CONS4(dB0,dB1,dB2,dB3, w1);  // c=5
        ISSUE4(dB0,dB1,dB2,dB3, m3);  MWLD(m1,w1, 9);   CONS4(dA0,dA1,dA2,dA3, w2);  // c=6
        ISSUE4(dA0,dA1,dA2,dA3, m0);  MWLD(m2,w2,10);   CONS4(dB0,dB1,dB2,dB3, w3);  // c=7
        ISSUE4(dB0,dB1,dB2,dB3, m1);  MWLD(m3,w3,11);   CONS4(dA0,dA1,dA2,dA3, w0);  // c=8
        ISSUE4(dA0,dA1,dA2,dA3, m2);  MWLD(m0,w0,12);   CONS4(dB0,dB1,dB2,dB3, w1);  // c=9
        ISSUE4(dB0,dB1,dB2,dB3, m3);  MWLD(m1,w1,13);   CONS4(dA0,dA1,dA2,dA3, w2);  // c=10
        ISSUE4(dA0,dA1,dA2,dA3, m0);  MWLD(m2,w2,14);   CONS4(dB0,dB1,dB2,dB3, w3);  // c=11
        ISSUE4(dB0,dB1,dB2,dB3, m1);  MWLD(m3,w3,15);   CONS4(dA0,dA1,dA2,dA3, w0);  // c=12
        ISSUE4(dA0,dA1,dA2,dA3, m2);                    CONS4(dB0,dB1,dB2,dB3, w1);  // c=13
        ISSUE4(dB0,dB1,dB2,dB3, m3);                    CONS4(dA0,dA1,dA2,dA3, w2);  // c=14
                                                        CONS4(dB0,dB1,dB2,dB3, w3);  // c=15

        float* op = out + (size_t)r0 * OUT_DIM + o;
        op[0 * OUT_DIM] = acc0;
        op[1 * OUT_DIM] = acc1;
        op[2 * OUT_DIM] = acc2;
        op[3 * OUT_DIM] = acc3;
        op[4 * OUT_DIM] = acc4;
        op[5 * OUT_DIM] = acc5;
        op[6 * OUT_DIM] = acc6;
        op[7 * OUT_DIM] = acc7;
    }
#undef CONSUME
#undef ISSUE4
#undef CONS4
#undef MWLD
#undef LDQ
}

extern "C" void kernel_launch(void* const* d_in, const int* in_sizes, int n_in,
                              void* d_out, int out_size, void* d_ws, size_t ws_size,
                              hipStream_t stream) {
    const float* inp  = (const float*)d_in[0];
    const float* W    = (const float*)d_in[1];
    const int*   M    = (const int*)d_in[2];
    const float* bias = (const float*)d_in[3];
    float* out = (float*)d_out;

    const int n_rows = in_sizes[0] / IN_DIM;          // 4096
    dim3 grid(n_rows / ROWS), block(NTHREADS);

    const bool use_t = ws_size >= 2 * MT_BYTES;
    if (use_t) {
        int*   Mt = (int*)d_ws;
        float* Wt = (float*)((char*)d_ws + MT_BYTES);
        schedule_mw<<<dim3(OUT_DIM / 4), dim3(256), 0, stream>>>(M, W, Mt, Wt);
        ffi_sparse_kernel<true><<<grid, block, 0, stream>>>(inp, W, M, bias,
                                                            (const int4*)Mt,
                                                            (const float4*)Wt, out);
    } else {
        ffi_sparse_kernel<false><<<grid, block, 0, stream>>>(inp, W, M, bias,
                                                             (const int4*)nullptr,
                                                             (const float4*)nullptr, out);
    }
}